// Round 1
// baseline (550.117 us; speedup 1.0000x reference)
//
#include <hip/hip_runtime.h>

// Problem: T=512, B=64, I=H=512.
// x[t,b,h] = sum_i input[t,b,i]*W_ih[h,i] + b_ih[h] + sum_j hidden[t,b,j]*W_hh[h,j] + b_hh[h]
// then LIF scan over t per (b,h): v += (x - v)/2; spike = v>=1; v = (1-spike)*v.
// Flattened GEMM: M = T*B = 32768 rows (row m = t*B+b), N = 512, two K=512 phases.

constexpr int Mtot = 32768;
constexpr int Ntot = 512;
constexpr int Kd   = 512;   // per phase
constexpr int BM = 128, BN = 64, BK = 32;

// XOR swizzle: 16B-chunk within a row permuted by ((row>>3)^row)&7.
// Verified conflict-free for this kernel's read pattern (rows 8-apart for A,
// 4-apart for W) and for the dense write pattern.
__device__ __forceinline__ int swz(int row, int k) {
    int sw = ((row >> 3) ^ row) & 7;
    int c  = (k >> 2) ^ sw;
    return row * BK + (c << 2) + (k & 3);
}

// One K=512 phase: A is [M][512] row-major, W is [N][512] row-major.
// Accumulates ascending-k into acc (matches naive einsum order).
__device__ __forceinline__ void do_phase(
    const float* __restrict__ Ap, const float* __restrict__ Wp,
    float (&acc)[8][4], float* As, float* Ws,
    int m0, int n0, int tid, int tm, int tn)
{
    for (int k0 = 0; k0 < Kd; k0 += BK) {
        __syncthreads();
        // Stage A tile: 128 rows x 32 k = 4096 f32; 4 float4 per thread.
#pragma unroll
        for (int q = 0; q < 4; ++q) {
            int lin = q * 256 + tid;
            int row = lin >> 3, ch = lin & 7;
            float4 v4 = *(const float4*)(Ap + (size_t)(m0 + row) * Kd + k0 + ch * 4);
            *(float4*)(As + swz(row, ch * 4)) = v4;
        }
        // Stage W tile: 64 rows x 32 k = 2048 f32; 2 float4 per thread.
#pragma unroll
        for (int q = 0; q < 2; ++q) {
            int lin = q * 256 + tid;
            int row = lin >> 3, ch = lin & 7;
            float4 v4 = *(const float4*)(Wp + (size_t)(n0 + row) * Kd + k0 + ch * 4);
            *(float4*)(Ws + swz(row, ch * 4)) = v4;
        }
        __syncthreads();
#pragma unroll
        for (int k4 = 0; k4 < BK; k4 += 4) {
            float4 a[8], w[4];
#pragma unroll
            for (int i = 0; i < 8; ++i)
                a[i] = *(const float4*)(As + swz(tm * 8 + i, k4));
#pragma unroll
            for (int j = 0; j < 4; ++j)
                w[j] = *(const float4*)(Ws + swz(tn * 4 + j, k4));
#pragma unroll
            for (int i = 0; i < 8; ++i) {
#pragma unroll
                for (int j = 0; j < 4; ++j) {
                    acc[i][j] = fmaf(a[i].x, w[j].x, acc[i][j]);
                    acc[i][j] = fmaf(a[i].y, w[j].y, acc[i][j]);
                    acc[i][j] = fmaf(a[i].z, w[j].z, acc[i][j]);
                    acc[i][j] = fmaf(a[i].w, w[j].w, acc[i][j]);
                }
            }
        }
    }
}

__global__ __launch_bounds__(256, 2) void gemm_x(
    const float* __restrict__ A1, const float* __restrict__ A2,
    const float* __restrict__ W1, const float* __restrict__ bi,
    const float* __restrict__ W2, const float* __restrict__ bh,
    float* __restrict__ out)
{
    __shared__ float As[BM * BK];   // 16 KiB
    __shared__ float Ws[BN * BK];   // 8 KiB

    const int tid = threadIdx.x;
    const int bm = blockIdx.x >> 3;      // 256 M-tiles
    const int bn = blockIdx.x & 7;       // 8 N-tiles (keeps same-A blocks adjacent)
    const int m0 = bm * BM, n0 = bn * BN;
    const int tm = tid >> 4, tn = tid & 15;   // 16x16 threads, 8x4 outputs each

    float acc1[8][4];
    float acc2[8][4];
#pragma unroll
    for (int i = 0; i < 8; ++i)
#pragma unroll
        for (int j = 0; j < 4; ++j) { acc1[i][j] = 0.f; acc2[i][j] = 0.f; }

    do_phase(A1, W1, acc1, As, Ws, m0, n0, tid, tm, tn);
    do_phase(A2, W2, acc2, As, Ws, m0, n0, tid, tm, tn);

    // Epilogue: x = ((dot1 + b_ih) + dot2) + b_hh  (reference's exact add order)
    const float4 bi4 = *(const float4*)(bi + n0 + tn * 4);
    const float4 bh4 = *(const float4*)(bh + n0 + tn * 4);
#pragma unroll
    for (int i = 0; i < 8; ++i) {
        float4 o;
        o.x = ((acc1[i][0] + bi4.x) + acc2[i][0]) + bh4.x;
        o.y = ((acc1[i][1] + bi4.y) + acc2[i][1]) + bh4.y;
        o.z = ((acc1[i][2] + bi4.z) + acc2[i][2]) + bh4.z;
        o.w = ((acc1[i][3] + bi4.w) + acc2[i][3]) + bh4.w;
        *(float4*)(out + (size_t)(m0 + tm * 8 + i) * Ntot + n0 + tn * 4) = o;
    }
}

// In-place LIF scan: one thread per (b,h) lane, sequential over t.
// v = v + (x - v)*0.5 ; spike = (v - 1 >= 0) ; v = (1-spike)*v   (exact ref ops)
__global__ __launch_bounds__(256) void lif_scan(float* __restrict__ x)
{
    const int tid = blockIdx.x * blockDim.x + threadIdx.x;  // 0..32767
    float v = 0.f;
    for (int tb = 0; tb < 512; tb += 8) {
        float xv[8];
#pragma unroll
        for (int u = 0; u < 8; ++u)
            xv[u] = x[(tb + u) * 32768 + tid];
#pragma unroll
        for (int u = 0; u < 8; ++u) {
            v = v + (xv[u] - v) * 0.5f;
            float s = (v - 1.0f >= 0.0f) ? 1.0f : 0.0f;
            x[(tb + u) * 32768 + tid] = s;
            v = (1.0f - s) * v;
        }
    }
}

extern "C" void kernel_launch(void* const* d_in, const int* in_sizes, int n_in,
                              void* d_out, int out_size, void* d_ws, size_t ws_size,
                              hipStream_t stream) {
    const float* input  = (const float*)d_in[0];
    const float* hidden = (const float*)d_in[1];
    const float* W_ih   = (const float*)d_in[2];
    const float* b_ih   = (const float*)d_in[3];
    const float* W_hh   = (const float*)d_in[4];
    const float* b_hh   = (const float*)d_in[5];
    float* out = (float*)d_out;

    dim3 grid((Mtot / BM) * (Ntot / BN));   // 2048 blocks
    dim3 block(256);
    gemm_x<<<grid, block, 0, stream>>>(input, hidden, W_ih, b_ih, W_hh, b_hh, out);
    lif_scan<<<128, 256, 0, stream>>>(out);
}